// Round 1
// baseline (236.622 us; speedup 1.0000x reference)
//
#include <hip/hip_runtime.h>
#include <stdint.h>
#include <math.h>

#define NPIX   16384
#define SAMPLE 1024
#define NV     778
#define BATCH  64

// ---------------------------------------------------------------------------
// Threefry-2x32, 20 rounds — matches jax._src.prng lowering exactly.
// ---------------------------------------------------------------------------
__device__ __forceinline__ uint32_t rotl32(uint32_t v, int r) {
  return (v << r) | (v >> (32 - r));
}

__device__ __forceinline__ void threefry2x32(uint32_t ks0, uint32_t ks1,
                                             uint32_t x0, uint32_t x1,
                                             uint32_t& o0, uint32_t& o1) {
  uint32_t ks2 = ks0 ^ ks1 ^ 0x1BD11BDAu;
  x0 += ks0; x1 += ks1;
#define TF_R(r) { x0 += x1; x1 = rotl32(x1, (r)); x1 ^= x0; }
  TF_R(13) TF_R(15) TF_R(26) TF_R(6)
  x0 += ks1; x1 += ks2 + 1u;
  TF_R(17) TF_R(29) TF_R(16) TF_R(24)
  x0 += ks2; x1 += ks0 + 2u;
  TF_R(13) TF_R(15) TF_R(26) TF_R(6)
  x0 += ks0; x1 += ks1 + 3u;
  TF_R(17) TF_R(29) TF_R(16) TF_R(24)
  x0 += ks1; x1 += ks2 + 4u;
  TF_R(13) TF_R(15) TF_R(26) TF_R(6)
  x0 += ks2; x1 += ks0 + 5u;
#undef TF_R
  o0 = x0; o1 = x1;
}

// ---------------------------------------------------------------------------
// Kernel A: one block per batch. Computes gumbel scores (threefry-exact),
// radix-selects the top-1024 (lower-index tie-break, matching lax.top_k),
// and writes normalized xyz for the selected pixels to ws.
// Sort key: 48-bit  (monotone_f32_bits(score) << 16) | (16383 - p).
// PRNG variant: jax_threefry_partitionable=True path: bits = h0 ^ h1 of
// threefry(key, (0, flat_index)).  [Fallback if absmax ~0.02-0.2: legacy
// split-iota path h0(i, i+524288) / h1.]
// ---------------------------------------------------------------------------
__global__ __launch_bounds__(1024) void score_select_xyz(
    const float* __restrict__ real,
    const float* __restrict__ center,
    const float* __restrict__ M,
    const float* __restrict__ cube,
    float* __restrict__ pcl) {
  const int b = blockIdx.x;
  const int tid = threadIdx.x;

  __shared__ float sh_minv[6];      // rows 0,1 of M^{-1}
  __shared__ float sh_c[3];         // center
  __shared__ float sh_hb[3];        // cube/2
  __shared__ uint32_t hist[16];
  __shared__ uint64_t sh_prefix;
  __shared__ uint32_t sh_kneed;
  __shared__ uint32_t sh_cnt;

  if (tid == 0) {
    const float* m = M + (size_t)b * 9;
    float m00=m[0], m01=m[1], m02=m[2];
    float m10=m[3], m11=m[4], m12=m[5];
    float m20=m[6], m21=m[7], m22=m[8];
    float c00 = m11*m22 - m12*m21;
    float c10 = m12*m20 - m10*m22;
    float c20 = m10*m21 - m11*m20;
    float det = m00*c00 + m01*c10 + m02*c20;
    float id = 1.0f / det;
    sh_minv[0] = c00 * id;
    sh_minv[1] = (m02*m21 - m01*m22) * id;
    sh_minv[2] = (m01*m12 - m02*m11) * id;
    sh_minv[3] = c10 * id;
    sh_minv[4] = (m00*m22 - m02*m20) * id;
    sh_minv[5] = (m02*m10 - m00*m12) * id;
    sh_c[0] = center[b*3+0]; sh_c[1] = center[b*3+1]; sh_c[2] = center[b*3+2];
    sh_hb[0] = cube[b*3+0]*0.5f; sh_hb[1] = cube[b*3+1]*0.5f; sh_hb[2] = cube[b*3+2]*0.5f;
    sh_cnt = 0;
  }
  __syncthreads();

  const float* rb = real + (size_t)b * NPIX;
  uint64_t kk[16];
#pragma unroll
  for (int e = 0; e < 16; ++e) {
    int p = e * 1024 + tid;                 // coalesced across the block
    float img = rb[p];
    uint32_t g = (uint32_t)(b * NPIX + p);  // flat index into (64,16384)
    uint32_t h0, h1;
    threefry2x32(0u, 1u, 0u, g, h0, h1);    // key(1) -> (0,1); counts_hi = 0
    uint32_t bits = h0 ^ h1;                // partitionable 32-bit path
    float u = __uint_as_float((bits >> 9) | 0x3f800000u) - 1.0f;  // [0,1)
    float gum = -logf(-logf(u + 1e-20f) + 1e-20f);
    float score = (img <= 0.99f) ? gum : -INFINITY;
    uint32_t sb = __float_as_uint(score);
    uint32_t mp = (sb & 0x80000000u) ? ~sb : (sb | 0x80000000u);  // monotone map
    kk[e] = ((uint64_t)mp << 16) | (uint64_t)(16383 - p);
  }

  // MSB-first 4-bit radix select of the 1024th-largest 48-bit key.
  uint64_t prefix = 0;
  uint32_t kneed = SAMPLE;
  for (int nb = 11; nb >= 0; --nb) {
    const int shift = nb * 4;
    if (tid < 16) hist[tid] = 0;
    __syncthreads();
#pragma unroll
    for (int e = 0; e < 16; ++e) {
      uint64_t k = kk[e];
      if ((k >> (shift + 4)) == prefix)
        atomicAdd(&hist[(uint32_t)(k >> shift) & 15u], 1u);
    }
    __syncthreads();
    if (tid == 0) {
      uint32_t cum = 0;
      int pick = 0;
      for (int v = 15; v >= 0; --v) {
        cum += hist[v];
        if (cum >= kneed) { pick = v; break; }
      }
      sh_kneed = kneed - (cum - hist[pick]);
      sh_prefix = (prefix << 4) | (uint32_t)pick;
    }
    __syncthreads();
    prefix = sh_prefix;
    kneed = sh_kneed;
  }
  const uint64_t T = prefix;   // exact 1024th-largest key; keys are unique

  // Compact selected pixels and emit normalized xyz.
#pragma unroll
  for (int e = 0; e < 16; ++e) {
    if (kk[e] >= T) {
      uint32_t slot = atomicAdd(&sh_cnt, 1u);
      if (slot < SAMPLE) {
        int p = 16383 - (int)(kk[e] & 0x3FFFu);
        int i = p >> 7, j = p & 127;
        // mirror reference fp order: t = 2*idx/127 - 1; uv = (t+1)*64
        float tj = (2.0f * (float)j) / 127.0f - 1.0f;
        float ti = (2.0f * (float)i) / 127.0f - 1.0f;
        float u0 = (tj + 1.0f) * 64.0f;
        float u1 = (ti + 1.0f) * 64.0f;
        float d  = rb[p] * sh_hb[2] + sh_c[2];
        float w0 = sh_minv[0]*u0 + sh_minv[1]*u1 + sh_minv[2];
        float w1 = sh_minv[3]*u0 + sh_minv[4]*u1 + sh_minv[5];
        float x = (w0 - 320.0f) * d / 588.03f;
        float y = (w1 - 240.0f) * d / 587.07f;   // FLIP = 1
        float* o = pcl + ((size_t)b * SAMPLE + slot) * 3;
        o[0] = (x - sh_c[0]) / sh_hb[0];
        o[1] = (y - sh_c[1]) / sh_hb[1];
        o[2] = (d - sh_c[2]) / sh_hb[2];
      }
    }
  }
}

// ---------------------------------------------------------------------------
// Kernel B: symmetric nearest-neighbor sums. 4 blocks per batch (256 blocks
// total = 1/CU). verts + sampled cloud staged in LDS; inner loops are
// same-address broadcasts (conflict-free).
// ---------------------------------------------------------------------------
__device__ __forceinline__ float waveReduceSum(float v) {
#pragma unroll
  for (int off = 32; off > 0; off >>= 1) v += __shfl_down(v, off, 64);
  return v;
}

__global__ __launch_bounds__(256) void dist_kernel(
    const float* __restrict__ verts,
    const float* __restrict__ pcl,
    float* __restrict__ partials) {
  const int blk = blockIdx.x;
  const int b = blk >> 2;
  const int q = blk & 3;
  const int tid = threadIdx.x;

  __shared__ float sv[NV * 3];
  __shared__ float sp[SAMPLE * 3];
  __shared__ float red[8];

  const float* vb = verts + (size_t)b * NV * 3;
  const float* pb = pcl   + (size_t)b * SAMPLE * 3;
  for (int t = tid; t < NV * 3; t += 256) sv[t] = vb[t];
  for (int t = tid; t < SAMPLE * 3; t += 256) sp[t] = pb[t];
  __syncthreads();

  // Phase A: this block's 256 points, min over all 778 verts.
  float sumA;
  {
    int pidx = q * 256 + tid;
    float px = sp[pidx*3], py = sp[pidx*3+1], pz = sp[pidx*3+2];
    float mn = INFINITY;
#pragma unroll 4
    for (int v = 0; v < NV; ++v) {
      float dx = px - sv[v*3], dy = py - sv[v*3+1], dz = pz - sv[v*3+2];
      float d2 = dx*dx + dy*dy + dz*dz;
      mn = fminf(mn, d2);
    }
    sumA = mn;
  }

  // Phase B: verts v = 4*tid + q, min over all 1024 points.
  float sumB = 0.0f;
  {
    int v = 4 * tid + q;
    if (v < NV) {
      float vx = sv[v*3], vy = sv[v*3+1], vz = sv[v*3+2];
      float mn = INFINITY;
#pragma unroll 4
      for (int pp = 0; pp < SAMPLE; ++pp) {
        float dx = sp[pp*3] - vx, dy = sp[pp*3+1] - vy, dz = sp[pp*3+2] - vz;
        float d2 = dx*dx + dy*dy + dz*dz;
        mn = fminf(mn, d2);
      }
      sumB = mn;
    }
  }

  float a = waveReduceSum(sumA);
  float bb = waveReduceSum(sumB);
  int wave = tid >> 6, lane = tid & 63;
  if (lane == 0) { red[wave*2] = a; red[wave*2+1] = bb; }
  __syncthreads();
  if (tid == 0) {
    partials[blk*2+0] = red[0] + red[2] + red[4] + red[6];
    partials[blk*2+1] = red[1] + red[3] + red[5] + red[7];
  }
}

// ---------------------------------------------------------------------------
// Kernel C: reduce 256 partial pairs, write the scalar loss.
// ---------------------------------------------------------------------------
__global__ __launch_bounds__(256) void finalize_kernel(
    const float* __restrict__ partials, float* __restrict__ out) {
  const int tid = threadIdx.x;
  __shared__ float red[8];
  float a = partials[tid*2+0];
  float bsum = partials[tid*2+1];
  a = waveReduceSum(a);
  bsum = waveReduceSum(bsum);
  int wave = tid >> 6, lane = tid & 63;
  if (lane == 0) { red[wave*2] = a; red[wave*2+1] = bsum; }
  __syncthreads();
  if (tid == 0) {
    float A = red[0] + red[2] + red[4] + red[6];
    float B = red[1] + red[3] + red[5] + red[7];
    out[0] = A / (float)(BATCH * SAMPLE) + B / (float)(BATCH * NV);
  }
}

extern "C" void kernel_launch(void* const* d_in, const int* in_sizes, int n_in,
                              void* d_out, int out_size, void* d_ws, size_t ws_size,
                              hipStream_t stream) {
  const float* real   = (const float*)d_in[0];
  // d_in[1] = synth (unused), d_in[3] = faces (unused)
  const float* verts  = (const float*)d_in[2];
  const float* center = (const float*)d_in[4];
  const float* M      = (const float*)d_in[5];
  const float* cube   = (const float*)d_in[6];

  float* pcl      = (float*)d_ws;                                   // 64*1024*3 f32
  float* partials = (float*)((char*)d_ws +
                     (size_t)BATCH * SAMPLE * 3 * sizeof(float));   // 256*2 f32
  float* out = (float*)d_out;

  score_select_xyz<<<dim3(BATCH), dim3(1024), 0, stream>>>(real, center, M, cube, pcl);
  dist_kernel<<<dim3(BATCH * 4), dim3(256), 0, stream>>>(verts, pcl, partials);
  finalize_kernel<<<dim3(1), dim3(256), 0, stream>>>(partials, out);
}

// Round 2
// 127.030 us; speedup vs baseline: 1.8627x; 1.8627x over previous
//
#include <hip/hip_runtime.h>
#include <stdint.h>
#include <math.h>

#define NPIX   16384
#define SAMPLE 1024
#define NV     778
#define BATCH  64

// ---------------------------------------------------------------------------
// Threefry-2x32, 20 rounds — matches jax._src.prng lowering exactly.
// ---------------------------------------------------------------------------
__device__ __forceinline__ uint32_t rotl32(uint32_t v, int r) {
  return (v << r) | (v >> (32 - r));
}

__device__ __forceinline__ void threefry2x32(uint32_t ks0, uint32_t ks1,
                                             uint32_t x0, uint32_t x1,
                                             uint32_t& o0, uint32_t& o1) {
  uint32_t ks2 = ks0 ^ ks1 ^ 0x1BD11BDAu;
  x0 += ks0; x1 += ks1;
#define TF_R(r) { x0 += x1; x1 = rotl32(x1, (r)); x1 ^= x0; }
  TF_R(13) TF_R(15) TF_R(26) TF_R(6)
  x0 += ks1; x1 += ks2 + 1u;
  TF_R(17) TF_R(29) TF_R(16) TF_R(24)
  x0 += ks2; x1 += ks0 + 2u;
  TF_R(13) TF_R(15) TF_R(26) TF_R(6)
  x0 += ks0; x1 += ks1 + 3u;
  TF_R(17) TF_R(29) TF_R(16) TF_R(24)
  x0 += ks1; x1 += ks2 + 4u;
  TF_R(13) TF_R(15) TF_R(26) TF_R(6)
  x0 += ks2; x1 += ks0 + 5u;
#undef TF_R
  o0 = x0; o1 = x1;
}

__device__ __forceinline__ float waveReduceSum(float v) {
#pragma unroll
  for (int off = 32; off > 0; off >>= 1) v += __shfl_down(v, off, 64);
  return v;
}

// ---------------------------------------------------------------------------
// K1: one thread per pixel — monotone-mapped gumbel score bits (exact
// threefry partitionable path). 1,048,576 threads.
// ---------------------------------------------------------------------------
__global__ __launch_bounds__(256) void score_kernel(
    const float* __restrict__ real, uint32_t* __restrict__ mp_out) {
  const int idx = blockIdx.x * 256 + threadIdx.x;   // flat (b, p)
  float img = real[idx];
  uint32_t h0, h1;
  threefry2x32(0u, 1u, 0u, (uint32_t)idx, h0, h1);  // key(1)=(0,1), hi-count=0
  uint32_t bits = h0 ^ h1;
  float u = __uint_as_float((bits >> 9) | 0x3f800000u) - 1.0f;
  float gum = -logf(-logf(u + 1e-20f) + 1e-20f);
  float score = (img <= 0.99f) ? gum : -INFINITY;
  uint32_t sb = __float_as_uint(score);
  uint32_t mp = (sb & 0x80000000u) ? ~sb : (sb | 0x80000000u);  // monotone
  mp_out[idx] = mp;
}

// ---------------------------------------------------------------------------
// K2: per-batch top-1024 selection. 48-bit key = (mp<<16)|(16383-p), 6-pass
// 8-bit MSB radix with 256-bucket LDS histogram + wave-parallel suffix scan.
// Emits normalized xyz (float4) for the selected pixels.
// ---------------------------------------------------------------------------
__global__ __launch_bounds__(1024) void select_kernel(
    const uint32_t* __restrict__ mp_in,
    const float* __restrict__ real,
    const float* __restrict__ center,
    const float* __restrict__ M,
    const float* __restrict__ cube,
    float4* __restrict__ pcl4) {
  const int b = blockIdx.x;
  const int tid = threadIdx.x;

  __shared__ uint32_t hist[256];
  __shared__ float sh_minv[6];
  __shared__ float sh_c[3];
  __shared__ float sh_hb[3];
  __shared__ uint64_t sh_prefix;
  __shared__ uint32_t sh_kneed;
  __shared__ uint32_t sh_cnt;

  if (tid == 0) {
    const float* m = M + (size_t)b * 9;
    float m00=m[0], m01=m[1], m02=m[2];
    float m10=m[3], m11=m[4], m12=m[5];
    float m20=m[6], m21=m[7], m22=m[8];
    float c00 = m11*m22 - m12*m21;
    float c10 = m12*m20 - m10*m22;
    float c20 = m10*m21 - m11*m20;
    float det = m00*c00 + m01*c10 + m02*c20;
    float id = 1.0f / det;
    sh_minv[0] = c00 * id;
    sh_minv[1] = (m02*m21 - m01*m22) * id;
    sh_minv[2] = (m01*m12 - m02*m11) * id;
    sh_minv[3] = c10 * id;
    sh_minv[4] = (m00*m22 - m02*m20) * id;
    sh_minv[5] = (m02*m10 - m00*m12) * id;
    sh_c[0] = center[b*3+0]; sh_c[1] = center[b*3+1]; sh_c[2] = center[b*3+2];
    sh_hb[0] = cube[b*3+0]*0.5f; sh_hb[1] = cube[b*3+1]*0.5f; sh_hb[2] = cube[b*3+2]*0.5f;
    sh_cnt = 0;
  }

  const uint32_t* mb = mp_in + (size_t)b * NPIX;
  uint64_t kk[16];
#pragma unroll
  for (int e = 0; e < 16; ++e) {
    int p = e * 1024 + tid;
    uint32_t mp = mb[p];
    kk[e] = ((uint64_t)mp << 16) | (uint64_t)(16383 - p);
  }

  uint64_t prefix = 0;
  uint32_t kneed = SAMPLE;
  for (int pass = 0; pass < 6; ++pass) {
    const int shift = 40 - pass * 8;
    if (tid < 256) hist[tid] = 0;
    __syncthreads();
#pragma unroll
    for (int e = 0; e < 16; ++e) {
      uint64_t k = kk[e];
      if ((k >> (shift + 8)) == prefix)
        atomicAdd(&hist[(uint32_t)(k >> shift) & 255u], 1u);
    }
    __syncthreads();
    if (tid < 64) {
      const int l = tid;
      uint32_t h0 = hist[l*4+0], h1 = hist[l*4+1], h2 = hist[l*4+2], h3 = hist[l*4+3];
      uint32_t t = h0 + h1 + h2 + h3;
      uint32_t sfx = t;
#pragma unroll
      for (int off = 1; off < 64; off <<= 1) {
        uint32_t u = __shfl_down(sfx, off, 64);
        if (l + off < 64) sfx += u;
      }
      uint32_t above = sfx - t;   // sum of buckets in lanes > l
      uint32_t s3 = above + h3;
      uint32_t s2 = s3 + h2;
      uint32_t s1 = s2 + h1;
      uint32_t s0 = s1 + h0;
      int c = -1; uint32_t sc = 0, hc = 0;
      if      (s3 >= kneed) { c = 3; sc = s3; hc = h3; }
      else if (s2 >= kneed) { c = 2; sc = s2; hc = h2; }
      else if (s1 >= kneed) { c = 1; sc = s1; hc = h1; }
      else if (s0 >= kneed) { c = 0; sc = s0; hc = h0; }
      unsigned long long mask = __ballot(c >= 0);
      int hl = 63 - __clzll(mask);
      if (l == hl) {
        sh_prefix = (prefix << 8) | (uint64_t)(uint32_t)(l * 4 + c);
        sh_kneed = kneed - (sc - hc);
      }
    }
    __syncthreads();
    prefix = sh_prefix;
    kneed = sh_kneed;
  }
  const uint64_t T = prefix;  // exact 1024th-largest key (keys unique)

  const float* rb = real + (size_t)b * NPIX;
#pragma unroll
  for (int e = 0; e < 16; ++e) {
    if (kk[e] >= T) {
      uint32_t slot = atomicAdd(&sh_cnt, 1u);
      if (slot < SAMPLE) {
        int p = 16383 - (int)(kk[e] & 0xFFFFu);
        int i = p >> 7, j = p & 127;
        float tj = (2.0f * (float)j) / 127.0f - 1.0f;
        float ti = (2.0f * (float)i) / 127.0f - 1.0f;
        float u0 = (tj + 1.0f) * 64.0f;
        float u1 = (ti + 1.0f) * 64.0f;
        float d  = rb[p] * sh_hb[2] + sh_c[2];
        float w0 = sh_minv[0]*u0 + sh_minv[1]*u1 + sh_minv[2];
        float w1 = sh_minv[3]*u0 + sh_minv[4]*u1 + sh_minv[5];
        float x = (w0 - 320.0f) * d / 588.03f;
        float y = (w1 - 240.0f) * d / 587.07f;
        float4 o;
        o.x = (x - sh_c[0]) / sh_hb[0];
        o.y = (y - sh_c[1]) / sh_hb[1];
        o.z = (d - sh_c[2]) / sh_hb[2];
        o.w = 0.0f;
        pcl4[(size_t)b * SAMPLE + slot] = o;
      }
    }
  }
}

// ---------------------------------------------------------------------------
// K3: chamfer sums. Blocks 0..511: direction A (point->vert min), 128 points
// per block, 8-way vert split in-block, 4 points/thread register tile.
// Blocks 512..959: direction B (vert->point min), 128 verts per block
// (64 x 7 slices), 8-way point split, 4 verts/thread.
// Inner loop: one broadcast ds_read_b128 per iteration serving 4 reg-tiled
// distance updates. Per-block partial sums written to ws.
// ---------------------------------------------------------------------------
#define NA_BLOCKS 512
#define NB_SLICES 7
#define NB_BLOCKS (BATCH * NB_SLICES)

__global__ __launch_bounds__(256, 4) void dist_kernel(
    const float* __restrict__ verts,
    const float4* __restrict__ pcl4,
    float* __restrict__ partials) {
  __shared__ __align__(16) uint8_t shbuf[20480];
  __shared__ float red[4];
  const int blk = blockIdx.x;
  const int tid = threadIdx.x;
  const int s = tid >> 5;    // split 0..7
  const int g = tid & 31;    // group 0..31
  float val = 0.0f;

  if (blk < NA_BLOCKS) {
    // ---- direction A: per-point min over verts ----
    const int b = blk >> 3, slice = blk & 7;
    float4* sv4 = (float4*)shbuf;                 // 778 * 16 = 12448 B
    float* pmin = (float*)(shbuf + 12448);        // 8*128*4 = 4096 B
    const float* vb = verts + (size_t)b * NV * 3;
    for (int v = tid; v < NV; v += 256) {
      float4 t;
      t.x = vb[v*3]; t.y = vb[v*3+1]; t.z = vb[v*3+2]; t.w = 0.0f;
      sv4[v] = t;
    }
    const float4* pb = pcl4 + (size_t)b * SAMPLE + slice * 128;
    float px[4], py[4], pz[4], mn[4];
#pragma unroll
    for (int j = 0; j < 4; ++j) {
      float4 q = pb[j * 32 + g];                  // lane-consecutive: coalesced
      px[j] = q.x; py[j] = q.y; pz[j] = q.z; mn[j] = INFINITY;
    }
    __syncthreads();
    const int vs = s * 98;
    const int ve = (vs + 98 < NV) ? vs + 98 : NV;
    for (int v = vs; v < ve; ++v) {
      float4 vv = sv4[v];                          // broadcast b128
#pragma unroll
      for (int j = 0; j < 4; ++j) {
        float dx = px[j] - vv.x, dy = py[j] - vv.y, dz = pz[j] - vv.z;
        float d2 = dx*dx + dy*dy + dz*dz;
        mn[j] = fminf(mn[j], d2);
      }
    }
#pragma unroll
    for (int j = 0; j < 4; ++j) pmin[s * 128 + j * 32 + g] = mn[j];
    __syncthreads();
    if (tid < 128) {
      float m = pmin[tid];
#pragma unroll
      for (int ss = 1; ss < 8; ++ss) m = fminf(m, pmin[ss * 128 + tid]);
      val = m;
    }
  } else {
    // ---- direction B: per-vert min over points ----
    const int bb = blk - NA_BLOCKS;
    const int b = bb / NB_SLICES, slice = bb % NB_SLICES;
    float4* sp4 = (float4*)shbuf;                 // 1024 * 16 = 16384 B
    float* vmin = (float*)(shbuf + 16384);        // 4096 B
    const float4* pcb = pcl4 + (size_t)b * SAMPLE;
    for (int i = tid; i < SAMPLE; i += 256) sp4[i] = pcb[i];
    const float* vb = verts + (size_t)b * NV * 3;
    const int vbase = slice * 128;
    float vx[4], vy[4], vz[4], mn[4];
    bool ok[4];
#pragma unroll
    for (int j = 0; j < 4; ++j) {
      int v = vbase + j * 32 + g;
      ok[j] = (v < NV);
      int vc = ok[j] ? v : 0;
      vx[j] = vb[vc*3]; vy[j] = vb[vc*3+1]; vz[j] = vb[vc*3+2];
      mn[j] = INFINITY;
    }
    __syncthreads();
    const int ps = s * 128;
    for (int i = 0; i < 128; ++i) {
      float4 pt = sp4[ps + i];                     // broadcast b128
#pragma unroll
      for (int j = 0; j < 4; ++j) {
        float dx = pt.x - vx[j], dy = pt.y - vy[j], dz = pt.z - vz[j];
        float d2 = dx*dx + dy*dy + dz*dz;
        mn[j] = fminf(mn[j], d2);
      }
    }
#pragma unroll
    for (int j = 0; j < 4; ++j) vmin[s * 128 + j * 32 + g] = mn[j];
    __syncthreads();
    if (tid < 128 && (vbase + tid) < NV) {
      float m = vmin[tid];
#pragma unroll
      for (int ss = 1; ss < 8; ++ss) m = fminf(m, vmin[ss * 128 + tid]);
      val = m;
    }
  }

  float r = waveReduceSum(val);
  if ((tid & 63) == 0) red[tid >> 6] = r;
  __syncthreads();
  if (tid == 0) partials[blk] = red[0] + red[1] + red[2] + red[3];
}

// ---------------------------------------------------------------------------
// K4: final reduction of 960 per-block partials into the scalar loss.
// ---------------------------------------------------------------------------
__global__ __launch_bounds__(1024) void finalize_kernel(
    const float* __restrict__ partials, float* __restrict__ out) {
  const int tid = threadIdx.x;
  __shared__ float redA[16], redB[16];
  float v = (tid < NA_BLOCKS + NB_BLOCKS) ? partials[tid] : 0.0f;
  float a  = (tid < NA_BLOCKS) ? v : 0.0f;
  float bs = (tid >= NA_BLOCKS) ? v : 0.0f;
  a  = waveReduceSum(a);
  bs = waveReduceSum(bs);
  int w = tid >> 6, lane = tid & 63;
  if (lane == 0) { redA[w] = a; redB[w] = bs; }
  __syncthreads();
  if (tid == 0) {
    float A = 0.0f, B = 0.0f;
#pragma unroll
    for (int i = 0; i < 16; ++i) { A += redA[i]; B += redB[i]; }
    out[0] = A / (float)(BATCH * SAMPLE) + B / (float)(BATCH * NV);
  }
}

extern "C" void kernel_launch(void* const* d_in, const int* in_sizes, int n_in,
                              void* d_out, int out_size, void* d_ws, size_t ws_size,
                              hipStream_t stream) {
  const float* real   = (const float*)d_in[0];
  // d_in[1] = synth (unused), d_in[3] = faces (unused)
  const float* verts  = (const float*)d_in[2];
  const float* center = (const float*)d_in[4];
  const float* M      = (const float*)d_in[5];
  const float* cube   = (const float*)d_in[6];

  uint32_t* mp   = (uint32_t*)d_ws;                                  // 4 MiB
  float4* pcl4   = (float4*)((char*)d_ws + (4u << 20));              // 1 MiB
  float* partials = (float*)((char*)d_ws + (5u << 20));              // 3.75 KiB
  float* out = (float*)d_out;

  score_kernel<<<dim3(BATCH * NPIX / 256), dim3(256), 0, stream>>>(real, mp);
  select_kernel<<<dim3(BATCH), dim3(1024), 0, stream>>>(mp, real, center, M, cube, pcl4);
  dist_kernel<<<dim3(NA_BLOCKS + NB_BLOCKS), dim3(256), 0, stream>>>(verts, pcl4, partials);
  finalize_kernel<<<dim3(1), dim3(1024), 0, stream>>>(partials, out);
}

// Round 3
// 120.208 us; speedup vs baseline: 1.9684x; 1.0567x over previous
//
#include <hip/hip_runtime.h>
#include <stdint.h>
#include <math.h>

#define NPIX   16384
#define SAMPLE 1024
#define NV     778
#define BATCH  64

// ---------------------------------------------------------------------------
// Threefry-2x32, 20 rounds — matches jax._src.prng lowering exactly.
// ---------------------------------------------------------------------------
__device__ __forceinline__ uint32_t rotl32(uint32_t v, int r) {
  return (v << r) | (v >> (32 - r));
}

__device__ __forceinline__ void threefry2x32(uint32_t ks0, uint32_t ks1,
                                             uint32_t x0, uint32_t x1,
                                             uint32_t& o0, uint32_t& o1) {
  uint32_t ks2 = ks0 ^ ks1 ^ 0x1BD11BDAu;
  x0 += ks0; x1 += ks1;
#define TF_R(r) { x0 += x1; x1 = rotl32(x1, (r)); x1 ^= x0; }
  TF_R(13) TF_R(15) TF_R(26) TF_R(6)
  x0 += ks1; x1 += ks2 + 1u;
  TF_R(17) TF_R(29) TF_R(16) TF_R(24)
  x0 += ks2; x1 += ks0 + 2u;
  TF_R(13) TF_R(15) TF_R(26) TF_R(6)
  x0 += ks0; x1 += ks1 + 3u;
  TF_R(17) TF_R(29) TF_R(16) TF_R(24)
  x0 += ks1; x1 += ks2 + 4u;
  TF_R(13) TF_R(15) TF_R(26) TF_R(6)
  x0 += ks2; x1 += ks0 + 5u;
#undef TF_R
  o0 = x0; o1 = x1;
}

__device__ __forceinline__ float waveReduceSum(float v) {
#pragma unroll
  for (int off = 32; off > 0; off >>= 1) v += __shfl_down(v, off, 64);
  return v;
}

// ---------------------------------------------------------------------------
// K1: per-pixel uniform bits (exact threefry partitionable path).
// Gumbel score is strictly monotone in u-bits, and the float gumbel's min
// step (>= e*2^-23) exceeds worst-case rounding + ulp in the reachable
// range, so ordering by (ubits, lower-index) equals JAX's top_k ordering
// of the float gumbel scores exactly. No logf needed.
// Output: uval = valid ? (bits>>9)+1 : 0   (0 sorts below all valid keys).
// ---------------------------------------------------------------------------
__global__ __launch_bounds__(256) void score_kernel(
    const float4* __restrict__ real4, uint4* __restrict__ uval4) {
  const int i = blockIdx.x * 256 + threadIdx.x;   // quad index, [0, 262144)
  float4 im = real4[i];
  const uint32_t base = (uint32_t)i * 4u;
  uint32_t h0, h1;
  uint4 o;
  threefry2x32(0u, 1u, 0u, base + 0u, h0, h1);
  o.x = (im.x <= 0.99f) ? (((h0 ^ h1) >> 9) + 1u) : 0u;
  threefry2x32(0u, 1u, 0u, base + 1u, h0, h1);
  o.y = (im.y <= 0.99f) ? (((h0 ^ h1) >> 9) + 1u) : 0u;
  threefry2x32(0u, 1u, 0u, base + 2u, h0, h1);
  o.z = (im.z <= 0.99f) ? (((h0 ^ h1) >> 9) + 1u) : 0u;
  threefry2x32(0u, 1u, 0u, base + 3u, h0, h1);
  o.w = (im.w <= 0.99f) ? (((h0 ^ h1) >> 9) + 1u) : 0u;
  uval4[i] = o;
}

// ---------------------------------------------------------------------------
// K2: per-batch exact top-1024 via single uniform 512-bucket histogram +
// wave-parallel suffix scan + tiny rank-select on the boundary bucket
// (~32 candidates expected). Emits normalized xyz (float4), unordered
// (both loss terms are set-reductions, order irrelevant).
// ---------------------------------------------------------------------------
__global__ __launch_bounds__(1024) void select_kernel(
    const uint32_t* __restrict__ uval,
    const float* __restrict__ real,
    const float* __restrict__ center,
    const float* __restrict__ M,
    const float* __restrict__ cube,
    float4* __restrict__ pcl4) {
  const int b = blockIdx.x;
  const int tid = threadIdx.x;
  const int lane = tid & 63;
  const int wv = tid >> 6;

  __shared__ uint32_t hist[512];
  __shared__ uint32_t wt[8], offs[8];
  __shared__ uint64_t cand[512];
  __shared__ float sh_minv[6], sh_c[3], sh_hb[3];
  __shared__ uint32_t sh_cnt, sh_ccnt, sh_bstar, sh_above;

  if (tid == 0) {
    const float* m = M + (size_t)b * 9;
    float m00=m[0], m01=m[1], m02=m[2];
    float m10=m[3], m11=m[4], m12=m[5];
    float m20=m[6], m21=m[7], m22=m[8];
    float c00 = m11*m22 - m12*m21;
    float c10 = m12*m20 - m10*m22;
    float c20 = m10*m21 - m11*m20;
    float det = m00*c00 + m01*c10 + m02*c20;
    float id = 1.0f / det;
    sh_minv[0] = c00 * id;
    sh_minv[1] = (m02*m21 - m01*m22) * id;
    sh_minv[2] = (m01*m12 - m02*m11) * id;
    sh_minv[3] = c10 * id;
    sh_minv[4] = (m00*m22 - m02*m20) * id;
    sh_minv[5] = (m02*m10 - m00*m12) * id;
    sh_c[0] = center[b*3+0]; sh_c[1] = center[b*3+1]; sh_c[2] = center[b*3+2];
    sh_hb[0] = cube[b*3+0]*0.5f; sh_hb[1] = cube[b*3+1]*0.5f; sh_hb[2] = cube[b*3+2]*0.5f;
    sh_cnt = 0; sh_ccnt = 0;
  }
  if (tid < 512) hist[tid] = 0;

  const uint4* mb4 = (const uint4*)(uval + (size_t)b * NPIX);
  uint32_t uv[16];
#pragma unroll
  for (int e4 = 0; e4 < 4; ++e4) {
    uint4 q = mb4[e4 * 1024 + tid];
    uv[e4*4+0] = q.x; uv[e4*4+1] = q.y; uv[e4*4+2] = q.z; uv[e4*4+3] = q.w;
  }
  __syncthreads();

  // 1 histogram pass over uniform top-9 bits — minimal contention.
#pragma unroll
  for (int e = 0; e < 16; ++e)
    if (uv[e]) atomicAdd(&hist[(uv[e] - 1u) >> 14], 1u);
  __syncthreads();

  // Wave-parallel suffix scan over 512 buckets.
  uint32_t cnt = 0, sfx = 0;
  if (tid < 512) {
    cnt = hist[tid];
    sfx = cnt;
#pragma unroll
    for (int off = 1; off < 64; off <<= 1) {
      uint32_t u = __shfl_down(sfx, off, 64);
      if (lane + off < 64) sfx += u;
    }
    if (lane == 0) wt[wv] = sfx;
  }
  __syncthreads();
  if (tid < 8) {
    uint32_t t = wt[tid], s = t;
#pragma unroll
    for (int off = 1; off < 8; off <<= 1) {
      uint32_t u = __shfl_down(s, off, 64);
      if (tid + off < 8) s += u;
    }
    offs[tid] = s - t;
  }
  __syncthreads();
  if (tid < 512) {
    uint32_t tot = sfx + offs[wv];     // keys in buckets >= tid
    uint32_t above = tot - cnt;        // keys in buckets >  tid
    if (tot >= SAMPLE && above < SAMPLE && cnt > 0) {
      sh_bstar = (uint32_t)tid;        // unique crossing bucket
      sh_above = above;
    }
  }
  __syncthreads();
  const int bstar = (int)sh_bstar;
  const uint32_t kneed = SAMPLE - sh_above;

  const float* rb = real + (size_t)b * NPIX;
  float4* ob = pcl4 + (size_t)b * SAMPLE;
  auto emit = [&](int p, uint32_t slot) {
    int i = p >> 7, j = p & 127;
    float tj = (2.0f * (float)j) / 127.0f - 1.0f;
    float ti = (2.0f * (float)i) / 127.0f - 1.0f;
    float u0 = (tj + 1.0f) * 64.0f;
    float u1 = (ti + 1.0f) * 64.0f;
    float d  = rb[p] * sh_hb[2] + sh_c[2];
    float w0 = sh_minv[0]*u0 + sh_minv[1]*u1 + sh_minv[2];
    float w1 = sh_minv[3]*u0 + sh_minv[4]*u1 + sh_minv[5];
    float x = (w0 - 320.0f) * d / 588.03f;
    float y = (w1 - 240.0f) * d / 587.07f;
    float4 o;
    o.x = (x - sh_c[0]) / sh_hb[0];
    o.y = (y - sh_c[1]) / sh_hb[1];
    o.z = (d - sh_c[2]) / sh_hb[2];
    o.w = 0.0f;
    ob[slot] = o;
  };

  // Compaction: wave-ballot aggregated (1 atomic per wave per class).
#pragma unroll
  for (int e = 0; e < 16; ++e) {
    uint32_t v = uv[e];
    int p = (e >> 2) * 4096 + (tid << 2) + (e & 3);
    int bk = v ? (int)((v - 1u) >> 14) : -1;
    bool hi = (bk > bstar);
    unsigned long long m = __ballot(hi);
    if (m) {
      int leader = __ffsll((unsigned long long)m) - 1;
      uint32_t base;
      if (lane == leader) base = atomicAdd(&sh_cnt, (uint32_t)__popcll(m));
      base = __shfl(base, leader, 64);
      if (hi) emit(p, base + (uint32_t)__popcll(m & ((1ull << lane) - 1ull)));
    }
    bool eqb = (bk == bstar);
    unsigned long long m2 = __ballot(eqb);
    if (m2) {
      int leader = __ffsll((unsigned long long)m2) - 1;
      uint32_t cb;
      if (lane == leader) cb = atomicAdd(&sh_ccnt, (uint32_t)__popcll(m2));
      cb = __shfl(cb, leader, 64);
      if (eqb) {
        uint32_t ci = cb + (uint32_t)__popcll(m2 & ((1ull << lane) - 1ull));
        if (ci < 512) cand[ci] = ((uint64_t)v << 14) | (uint64_t)(16383 - p);
      }
    }
  }
  __syncthreads();

  // Rank-select the kneed largest among the boundary-bucket candidates.
  uint32_t c = sh_ccnt; if (c > 512) c = 512;
  if (tid < 64) {
    for (uint32_t basei = 0; basei < c; basei += 64) {
      uint32_t i = basei + (uint32_t)lane;
      bool act = (i < c);
      uint64_t ki = act ? cand[i] : 0ull;
      uint32_t rank = 0;
      for (uint32_t j2 = 0; j2 < c; ++j2) rank += (cand[j2] > ki) ? 1u : 0u;
      bool sel = act && (rank < kneed);   // keys unique -> exactly kneed
      unsigned long long m = __ballot(sel);
      if (m) {
        int leader = __ffsll((unsigned long long)m) - 1;
        uint32_t base;
        if (lane == leader) base = atomicAdd(&sh_cnt, (uint32_t)__popcll(m));
        base = __shfl(base, leader, 64);
        if (sel) {
          int p = 16383 - (int)(ki & 0x3FFFull);
          emit(p, base + (uint32_t)__popcll(m & ((1ull << lane) - 1ull)));
        }
      }
    }
  }
}

// ---------------------------------------------------------------------------
// K3: chamfer sums. Blocks 0..511: direction A (point->vert min), 128 points
// per block, 8-way vert split, 4 points/thread register tile. Blocks
// 512..959: direction B (vert->point min), 128 verts per block, 8-way point
// split, 4 verts/thread. One broadcast ds_read_b128 per 4 reg-tiled updates.
// ---------------------------------------------------------------------------
#define NA_BLOCKS 512
#define NB_SLICES 7
#define NB_BLOCKS (BATCH * NB_SLICES)

__global__ __launch_bounds__(256, 4) void dist_kernel(
    const float* __restrict__ verts,
    const float4* __restrict__ pcl4,
    float* __restrict__ partials) {
  __shared__ __align__(16) uint8_t shbuf[20480];
  __shared__ float red[4];
  const int blk = blockIdx.x;
  const int tid = threadIdx.x;
  const int s = tid >> 5;
  const int g = tid & 31;
  float val = 0.0f;

  if (blk < NA_BLOCKS) {
    const int b = blk >> 3, slice = blk & 7;
    float4* sv4 = (float4*)shbuf;                 // 778*16 = 12448 B
    float* pmin = (float*)(shbuf + 12448);        // 4096 B
    const float* vb = verts + (size_t)b * NV * 3;
    for (int v = tid; v < NV; v += 256) {
      float4 t;
      t.x = vb[v*3]; t.y = vb[v*3+1]; t.z = vb[v*3+2]; t.w = 0.0f;
      sv4[v] = t;
    }
    const float4* pb = pcl4 + (size_t)b * SAMPLE + slice * 128;
    float px[4], py[4], pz[4], mn[4];
#pragma unroll
    for (int j = 0; j < 4; ++j) {
      float4 q = pb[j * 32 + g];
      px[j] = q.x; py[j] = q.y; pz[j] = q.z; mn[j] = INFINITY;
    }
    __syncthreads();
    const int vs = s * 98;
    const int ve = (vs + 98 < NV) ? vs + 98 : NV;
    for (int v = vs; v < ve; ++v) {
      float4 vv = sv4[v];
#pragma unroll
      for (int j = 0; j < 4; ++j) {
        float dx = px[j] - vv.x, dy = py[j] - vv.y, dz = pz[j] - vv.z;
        float d2 = dx*dx + dy*dy + dz*dz;
        mn[j] = fminf(mn[j], d2);
      }
    }
#pragma unroll
    for (int j = 0; j < 4; ++j) pmin[s * 128 + j * 32 + g] = mn[j];
    __syncthreads();
    if (tid < 128) {
      float m = pmin[tid];
#pragma unroll
      for (int ss = 1; ss < 8; ++ss) m = fminf(m, pmin[ss * 128 + tid]);
      val = m;
    }
  } else {
    const int bb = blk - NA_BLOCKS;
    const int b = bb / NB_SLICES, slice = bb % NB_SLICES;
    float4* sp4 = (float4*)shbuf;                 // 16384 B
    float* vmin = (float*)(shbuf + 16384);        // 4096 B
    const float4* pcb = pcl4 + (size_t)b * SAMPLE;
    for (int i = tid; i < SAMPLE; i += 256) sp4[i] = pcb[i];
    const float* vb = verts + (size_t)b * NV * 3;
    const int vbase = slice * 128;
    float vx[4], vy[4], vz[4], mn[4];
#pragma unroll
    for (int j = 0; j < 4; ++j) {
      int v = vbase + j * 32 + g;
      int vc = (v < NV) ? v : 0;
      vx[j] = vb[vc*3]; vy[j] = vb[vc*3+1]; vz[j] = vb[vc*3+2];
      mn[j] = INFINITY;
    }
    __syncthreads();
    const int ps = s * 128;
    for (int i = 0; i < 128; ++i) {
      float4 pt = sp4[ps + i];
#pragma unroll
      for (int j = 0; j < 4; ++j) {
        float dx = pt.x - vx[j], dy = pt.y - vy[j], dz = pt.z - vz[j];
        float d2 = dx*dx + dy*dy + dz*dz;
        mn[j] = fminf(mn[j], d2);
      }
    }
#pragma unroll
    for (int j = 0; j < 4; ++j) vmin[s * 128 + j * 32 + g] = mn[j];
    __syncthreads();
    if (tid < 128 && (vbase + tid) < NV) {
      float m = vmin[tid];
#pragma unroll
      for (int ss = 1; ss < 8; ++ss) m = fminf(m, vmin[ss * 128 + tid]);
      val = m;
    }
  }

  float r = waveReduceSum(val);
  if ((tid & 63) == 0) red[tid >> 6] = r;
  __syncthreads();
  if (tid == 0) partials[blk] = red[0] + red[1] + red[2] + red[3];
}

// ---------------------------------------------------------------------------
// K4: final reduction of 960 per-block partials into the scalar loss.
// ---------------------------------------------------------------------------
__global__ __launch_bounds__(1024) void finalize_kernel(
    const float* __restrict__ partials, float* __restrict__ out) {
  const int tid = threadIdx.x;
  __shared__ float redA[16], redB[16];
  float v = (tid < NA_BLOCKS + NB_BLOCKS) ? partials[tid] : 0.0f;
  float a  = (tid < NA_BLOCKS) ? v : 0.0f;
  float bs = (tid >= NA_BLOCKS) ? v : 0.0f;
  a  = waveReduceSum(a);
  bs = waveReduceSum(bs);
  int w = tid >> 6, lane = tid & 63;
  if (lane == 0) { redA[w] = a; redB[w] = bs; }
  __syncthreads();
  if (tid == 0) {
    float A = 0.0f, B = 0.0f;
#pragma unroll
    for (int i = 0; i < 16; ++i) { A += redA[i]; B += redB[i]; }
    out[0] = A / (float)(BATCH * SAMPLE) + B / (float)(BATCH * NV);
  }
}

extern "C" void kernel_launch(void* const* d_in, const int* in_sizes, int n_in,
                              void* d_out, int out_size, void* d_ws, size_t ws_size,
                              hipStream_t stream) {
  const float* real   = (const float*)d_in[0];
  // d_in[1] = synth (unused), d_in[3] = faces (unused)
  const float* verts  = (const float*)d_in[2];
  const float* center = (const float*)d_in[4];
  const float* M      = (const float*)d_in[5];
  const float* cube   = (const float*)d_in[6];

  uint32_t* uval  = (uint32_t*)d_ws;                                 // 4 MiB
  float4* pcl4    = (float4*)((char*)d_ws + (4u << 20));             // 1 MiB
  float* partials = (float*)((char*)d_ws + (5u << 20));              // 3.75 KiB
  float* out = (float*)d_out;

  score_kernel<<<dim3(BATCH * NPIX / 4 / 256), dim3(256), 0, stream>>>(
      (const float4*)real, (uint4*)uval);
  select_kernel<<<dim3(BATCH), dim3(1024), 0, stream>>>(
      uval, real, center, M, cube, pcl4);
  dist_kernel<<<dim3(NA_BLOCKS + NB_BLOCKS), dim3(256), 0, stream>>>(
      verts, pcl4, partials);
  finalize_kernel<<<dim3(1), dim3(1024), 0, stream>>>(partials, out);
}

// Round 4
// 119.715 us; speedup vs baseline: 1.9766x; 1.0041x over previous
//
#include <hip/hip_runtime.h>
#include <stdint.h>
#include <math.h>

#define NPIX   16384
#define SAMPLE 1024
#define NV     778
#define BATCH  64

#define A_SCALE (1.0f / (float)(BATCH * SAMPLE))
#define B_SCALE (1.0f / (float)(BATCH * NV))

// ---------------------------------------------------------------------------
// Threefry-2x32, 20 rounds — matches jax._src.prng lowering exactly.
// ---------------------------------------------------------------------------
__device__ __forceinline__ uint32_t rotl32(uint32_t v, int r) {
  return (v << r) | (v >> (32 - r));
}

__device__ __forceinline__ uint32_t threefry_bits(uint32_t g) {
  // key(1) = (0,1); partitionable path: x0 = counts_hi = 0, x1 = g; out h0^h1.
  uint32_t ks0 = 0u, ks1 = 1u;
  uint32_t ks2 = ks0 ^ ks1 ^ 0x1BD11BDAu;
  uint32_t x0 = 0u + ks0, x1 = g + ks1;
#define TF_R(r) { x0 += x1; x1 = rotl32(x1, (r)); x1 ^= x0; }
  TF_R(13) TF_R(15) TF_R(26) TF_R(6)
  x0 += ks1; x1 += ks2 + 1u;
  TF_R(17) TF_R(29) TF_R(16) TF_R(24)
  x0 += ks2; x1 += ks0 + 2u;
  TF_R(13) TF_R(15) TF_R(26) TF_R(6)
  x0 += ks0; x1 += ks1 + 3u;
  TF_R(17) TF_R(29) TF_R(16) TF_R(24)
  x0 += ks1; x1 += ks2 + 4u;
  TF_R(13) TF_R(15) TF_R(26) TF_R(6)
  x0 += ks2; x1 += ks0 + 5u;
#undef TF_R
  return x0 ^ x1;
}

__device__ __forceinline__ float waveReduceSum(float v) {
#pragma unroll
  for (int off = 32; off > 0; off >>= 1) v += __shfl_down(v, off, 64);
  return v;
}

// ---------------------------------------------------------------------------
// K1 (fused score+select): one block per batch. Threefry u-bits computed
// in-register (gumbel is strictly monotone in u-bits; float-gumbel min-step
// >= e*2^-23 exceeds rounding error, so (ubits, lower-index) ordering ==
// JAX's top_k of float gumbels). Single uniform 512-bucket histogram +
// wave suffix scan + rank-select on boundary bucket. Emits normalized xyz.
// ---------------------------------------------------------------------------
__global__ __launch_bounds__(1024) void select_kernel(
    const float4* __restrict__ real4,
    const float* __restrict__ center,
    const float* __restrict__ M,
    const float* __restrict__ cube,
    float4* __restrict__ pcl4) {
  const int b = blockIdx.x;
  const int tid = threadIdx.x;
  const int lane = tid & 63;
  const int wv = tid >> 6;

  __shared__ uint32_t hist[512];
  __shared__ uint32_t wt[8], offs[8];
  __shared__ uint64_t cand[512];
  __shared__ float candrv[512];
  __shared__ float sh_minv[6], sh_c[3], sh_hb[3];
  __shared__ uint32_t sh_cnt, sh_ccnt, sh_bstar, sh_above;

  if (tid == 0) {
    const float* m = M + (size_t)b * 9;
    float m00=m[0], m01=m[1], m02=m[2];
    float m10=m[3], m11=m[4], m12=m[5];
    float m20=m[6], m21=m[7], m22=m[8];
    float c00 = m11*m22 - m12*m21;
    float c10 = m12*m20 - m10*m22;
    float c20 = m10*m21 - m11*m20;
    float det = m00*c00 + m01*c10 + m02*c20;
    float id = 1.0f / det;
    sh_minv[0] = c00 * id;
    sh_minv[1] = (m02*m21 - m01*m22) * id;
    sh_minv[2] = (m01*m12 - m02*m11) * id;
    sh_minv[3] = c10 * id;
    sh_minv[4] = (m00*m22 - m02*m20) * id;
    sh_minv[5] = (m02*m10 - m00*m12) * id;
    sh_c[0] = center[b*3+0]; sh_c[1] = center[b*3+1]; sh_c[2] = center[b*3+2];
    sh_hb[0] = cube[b*3+0]*0.5f; sh_hb[1] = cube[b*3+1]*0.5f; sh_hb[2] = cube[b*3+2]*0.5f;
    sh_cnt = 0; sh_ccnt = 0;
  }
  if (tid < 512) hist[tid] = 0;

  // In-register scoring: 16 pixels/thread, p = e4*4096 + tid*4 + c.
  uint32_t uv[16];
  float    rv[16];
  const float4* rb4 = real4 + (size_t)b * (NPIX / 4);
#pragma unroll
  for (int e4 = 0; e4 < 4; ++e4) {
    float4 im = rb4[e4 * 1024 + tid];
    uint32_t base = (uint32_t)(b * NPIX + e4 * 4096) + (uint32_t)(tid << 2);
    rv[e4*4+0] = im.x; rv[e4*4+1] = im.y; rv[e4*4+2] = im.z; rv[e4*4+3] = im.w;
    uv[e4*4+0] = (im.x <= 0.99f) ? ((threefry_bits(base + 0u) >> 9) + 1u) : 0u;
    uv[e4*4+1] = (im.y <= 0.99f) ? ((threefry_bits(base + 1u) >> 9) + 1u) : 0u;
    uv[e4*4+2] = (im.z <= 0.99f) ? ((threefry_bits(base + 2u) >> 9) + 1u) : 0u;
    uv[e4*4+3] = (im.w <= 0.99f) ? ((threefry_bits(base + 3u) >> 9) + 1u) : 0u;
  }
  __syncthreads();

  // Histogram over uniform top-9 bits.
#pragma unroll
  for (int e = 0; e < 16; ++e)
    if (uv[e]) atomicAdd(&hist[(uv[e] - 1u) >> 14], 1u);
  __syncthreads();

  // Wave-parallel suffix scan over 512 buckets.
  uint32_t cnt = 0, sfx = 0;
  if (tid < 512) {
    cnt = hist[tid];
    sfx = cnt;
#pragma unroll
    for (int off = 1; off < 64; off <<= 1) {
      uint32_t u = __shfl_down(sfx, off, 64);
      if (lane + off < 64) sfx += u;
    }
    if (lane == 0) wt[wv] = sfx;
  }
  __syncthreads();
  if (tid < 8) {
    uint32_t t = wt[tid], s = t;
#pragma unroll
    for (int off = 1; off < 8; off <<= 1) {
      uint32_t u = __shfl_down(s, off, 64);
      if (tid + off < 8) s += u;
    }
    offs[tid] = s - t;
  }
  __syncthreads();
  if (tid < 512) {
    uint32_t tot = sfx + offs[wv];   // keys in buckets >= tid
    uint32_t above = tot - cnt;      // keys in buckets >  tid
    if (tot >= SAMPLE && above < SAMPLE && cnt > 0) {
      sh_bstar = (uint32_t)tid;
      sh_above = above;
    }
  }
  __syncthreads();
  const int bstar = (int)sh_bstar;
  const uint32_t kneed = SAMPLE - sh_above;

  float4* ob = pcl4 + (size_t)b * SAMPLE;
  auto emit = [&](int p, float depth01, uint32_t slot) {
    int i = p >> 7, j = p & 127;
    float tj = (2.0f * (float)j) / 127.0f - 1.0f;
    float ti = (2.0f * (float)i) / 127.0f - 1.0f;
    float u0 = (tj + 1.0f) * 64.0f;
    float u1 = (ti + 1.0f) * 64.0f;
    float d  = depth01 * sh_hb[2] + sh_c[2];
    float w0 = sh_minv[0]*u0 + sh_minv[1]*u1 + sh_minv[2];
    float w1 = sh_minv[3]*u0 + sh_minv[4]*u1 + sh_minv[5];
    float x = (w0 - 320.0f) * d / 588.03f;
    float y = (w1 - 240.0f) * d / 587.07f;
    float4 o;
    o.x = (x - sh_c[0]) / sh_hb[0];
    o.y = (y - sh_c[1]) / sh_hb[1];
    o.z = (d - sh_c[2]) / sh_hb[2];
    o.w = 0.0f;
    ob[slot] = o;
  };

  // Wave-ballot-aggregated compaction (1 atomic/wave per class per iter).
#pragma unroll
  for (int e = 0; e < 16; ++e) {
    uint32_t v = uv[e];
    int p = (e >> 2) * 4096 + (tid << 2) + (e & 3);
    int bk = v ? (int)((v - 1u) >> 14) : -1;
    bool hi = (bk > bstar);
    unsigned long long m = __ballot(hi);
    if (m) {
      int leader = __ffsll((unsigned long long)m) - 1;
      uint32_t base;
      if (lane == leader) base = atomicAdd(&sh_cnt, (uint32_t)__popcll(m));
      base = __shfl(base, leader, 64);
      if (hi) emit(p, rv[e], base + (uint32_t)__popcll(m & ((1ull << lane) - 1ull)));
    }
    bool eqb = (bk == bstar);
    unsigned long long m2 = __ballot(eqb);
    if (m2) {
      int leader = __ffsll((unsigned long long)m2) - 1;
      uint32_t cb;
      if (lane == leader) cb = atomicAdd(&sh_ccnt, (uint32_t)__popcll(m2));
      cb = __shfl(cb, leader, 64);
      if (eqb) {
        uint32_t ci = cb + (uint32_t)__popcll(m2 & ((1ull << lane) - 1ull));
        if (ci < 512) {
          cand[ci] = ((uint64_t)v << 14) | (uint64_t)(16383 - p);
          candrv[ci] = rv[e];
        }
      }
    }
  }
  __syncthreads();

  // Rank-select the kneed largest among the boundary-bucket candidates.
  uint32_t c = sh_ccnt; if (c > 512) c = 512;
  if (tid < 64) {
    for (uint32_t basei = 0; basei < c; basei += 64) {
      uint32_t i = basei + (uint32_t)lane;
      bool act = (i < c);
      uint64_t ki = act ? cand[i] : 0ull;
      uint32_t rank = 0;
      for (uint32_t j2 = 0; j2 < c; ++j2) rank += (cand[j2] > ki) ? 1u : 0u;
      bool sel = act && (rank < kneed);   // keys unique -> exactly kneed
      unsigned long long m = __ballot(sel);
      if (m) {
        int leader = __ffsll((unsigned long long)m) - 1;
        uint32_t base;
        if (lane == leader) base = atomicAdd(&sh_cnt, (uint32_t)__popcll(m));
        base = __shfl(base, leader, 64);
        if (sel) {
          int p = 16383 - (int)(ki & 0x3FFFull);
          emit(p, candrv[i], base + (uint32_t)__popcll(m & ((1ull << lane) - 1ull)));
        }
      }
    }
  }
}

// ---------------------------------------------------------------------------
// K2: chamfer sums, strength-reduced inner loop.
//   min_v (p-v)^2 = |p|^2 + min_v (|v|^2 - 2 p.v)
// LDS side staged as (-2x,-2y,-2z,|.|^2) -> inner pair = 3 chained fma + min.
// Blocks 0..511: dir A (8 point-groups of 128/batch, verts in LDS, 8-way
// vert split, 4 pts/thread). Blocks 512..959: dir B (7 vert-groups of
// 128/batch, points in LDS, 8-way point split, 4 verts/thread).
// Each block atomicAdds its pre-scaled partial into d_out[0].
// ---------------------------------------------------------------------------
#define NA_BLOCKS 512
#define NB_SLICES 7
#define NB_BLOCKS (BATCH * NB_SLICES)

__global__ __launch_bounds__(256, 4) void dist_kernel(
    const float* __restrict__ verts,
    const float4* __restrict__ pcl4,
    float* __restrict__ out) {
  __shared__ __align__(16) uint8_t shbuf[20992];
  __shared__ float red[4];
  const int blk = blockIdx.x;
  const int tid = threadIdx.x;
  const int s = tid >> 5;
  const int g = tid & 31;
  float val = 0.0f;

  if (blk < NA_BLOCKS) {
    const int b = blk >> 3, slice = blk & 7;
    float4* sv4 = (float4*)shbuf;                 // 778*16 = 12448 B
    float* pmin = (float*)(shbuf + 12448);        // 8*128*4 = 4096 B
    float* npl  = (float*)(shbuf + 16544);        // 128*4 = 512 B
    const float* vb = verts + (size_t)b * NV * 3;
    for (int v = tid; v < NV; v += 256) {
      float x = vb[v*3], y = vb[v*3+1], z = vb[v*3+2];
      float4 t;
      t.x = -2.0f*x; t.y = -2.0f*y; t.z = -2.0f*z; t.w = x*x + y*y + z*z;
      sv4[v] = t;
    }
    const float4* pb = pcl4 + (size_t)b * SAMPLE + slice * 128;
    float px[4], py[4], pz[4], np[4], mn[4];
#pragma unroll
    for (int j = 0; j < 4; ++j) {
      float4 q = pb[j * 32 + g];
      px[j] = q.x; py[j] = q.y; pz[j] = q.z;
      np[j] = q.x*q.x + q.y*q.y + q.z*q.z;
      mn[j] = INFINITY;
    }
    __syncthreads();
    const int vs = s * 98;
    const int ve = (vs + 98 < NV) ? vs + 98 : NV;
    for (int v = vs; v < ve; ++v) {
      float4 vv = sv4[v];                          // broadcast b128
#pragma unroll
      for (int j = 0; j < 4; ++j) {
        float t = fmaf(pz[j], vv.z, fmaf(py[j], vv.y, fmaf(px[j], vv.x, vv.w)));
        mn[j] = fminf(mn[j], t);
      }
    }
#pragma unroll
    for (int j = 0; j < 4; ++j) {
      pmin[s * 128 + j * 32 + g] = mn[j];
      if (s == 0) npl[j * 32 + g] = np[j];
    }
    __syncthreads();
    if (tid < 128) {
      float m = pmin[tid];
#pragma unroll
      for (int ss = 1; ss < 8; ++ss) m = fminf(m, pmin[ss * 128 + tid]);
      val = (m + npl[tid]) * A_SCALE;
    }
  } else {
    const int bb = blk - NA_BLOCKS;
    const int b = bb / NB_SLICES, slice = bb % NB_SLICES;
    float4* sp4 = (float4*)shbuf;                 // 1024*16 = 16384 B
    float* vmin = (float*)(shbuf + 16384);        // 4096 B
    float* nvl  = (float*)(shbuf + 20480);        // 512 B
    const float4* pcb = pcl4 + (size_t)b * SAMPLE;
    for (int i = tid; i < SAMPLE; i += 256) {
      float4 q = pcb[i];
      float4 t;
      t.x = -2.0f*q.x; t.y = -2.0f*q.y; t.z = -2.0f*q.z;
      t.w = q.x*q.x + q.y*q.y + q.z*q.z;
      sp4[i] = t;
    }
    const float* vb = verts + (size_t)b * NV * 3;
    const int vbase = slice * 128;
    float vx[4], vy[4], vz[4], nv[4], mn[4];
#pragma unroll
    for (int j = 0; j < 4; ++j) {
      int v = vbase + j * 32 + g;
      int vc = (v < NV) ? v : 0;
      vx[j] = vb[vc*3]; vy[j] = vb[vc*3+1]; vz[j] = vb[vc*3+2];
      nv[j] = vx[j]*vx[j] + vy[j]*vy[j] + vz[j]*vz[j];
      mn[j] = INFINITY;
    }
    __syncthreads();
    const int ps = s * 128;
    for (int i = 0; i < 128; ++i) {
      float4 pt = sp4[ps + i];                     // broadcast b128
#pragma unroll
      for (int j = 0; j < 4; ++j) {
        float t = fmaf(vz[j], pt.z, fmaf(vy[j], pt.y, fmaf(vx[j], pt.x, pt.w)));
        mn[j] = fminf(mn[j], t);
      }
    }
#pragma unroll
    for (int j = 0; j < 4; ++j) {
      vmin[s * 128 + j * 32 + g] = mn[j];
      if (s == 0) nvl[j * 32 + g] = nv[j];
    }
    __syncthreads();
    if (tid < 128 && (vbase + tid) < NV) {
      float m = vmin[tid];
#pragma unroll
      for (int ss = 1; ss < 8; ++ss) m = fminf(m, vmin[ss * 128 + tid]);
      val = (m + nvl[tid]) * B_SCALE;
    }
  }

  float r = waveReduceSum(val);
  if ((tid & 63) == 0) red[tid >> 6] = r;
  __syncthreads();
  if (tid == 0) atomicAdd(out, red[0] + red[1] + red[2] + red[3]);
}

extern "C" void kernel_launch(void* const* d_in, const int* in_sizes, int n_in,
                              void* d_out, int out_size, void* d_ws, size_t ws_size,
                              hipStream_t stream) {
  const float* real   = (const float*)d_in[0];
  // d_in[1] = synth (unused), d_in[3] = faces (unused)
  const float* verts  = (const float*)d_in[2];
  const float* center = (const float*)d_in[4];
  const float* M      = (const float*)d_in[5];
  const float* cube   = (const float*)d_in[6];

  float4* pcl4 = (float4*)d_ws;                    // 64*1024*16 B = 1 MiB
  float* out = (float*)d_out;

  hipMemsetAsync(out, 0, sizeof(float), stream);
  select_kernel<<<dim3(BATCH), dim3(1024), 0, stream>>>(
      (const float4*)real, center, M, cube, pcl4);
  dist_kernel<<<dim3(NA_BLOCKS + NB_BLOCKS), dim3(256), 0, stream>>>(
      verts, pcl4, out);
}